// Round 1
// baseline (1141.862 us; speedup 1.0000x reference)
//
#include <hip/hip_runtime.h>
#include <hip/hip_bf16.h>
#include <math.h>

#define BB 2
#define TT 1024
#define CC 768
#define HH 3072
#define NEXP 8
#define NTOK (BB*TT)        // 2048 tokens
#define NENT (NTOK*2)       // 4096 (token, k) entries

// ---------- helpers ----------
__device__ __forceinline__ unsigned short f2bf(float f) {
    unsigned int u = __float_as_uint(f);
    unsigned int r = (u + 0x7fffu + ((u >> 16) & 1u)) >> 16;
    return (unsigned short)r;
}
__device__ __forceinline__ float bf2f(unsigned short us) {
    return __uint_as_float(((unsigned int)us) << 16);
}
__device__ __forceinline__ float gelu_tanh(float v) {
    const float k0 = 0.7978845608028654f;   // sqrt(2/pi)
    const float k1 = 0.044715f;
    return 0.5f * v * (1.0f + tanhf(k0 * (v + k1 * v * v * v)));
}

// ---------- router: logits, softmax, top-2, renorm, bucket ----------
__global__ void router_kernel(const float* __restrict__ x,
                              const float* __restrict__ w_gate,
                              float* __restrict__ top_p,
                              int* __restrict__ counts,
                              int* __restrict__ tok_list) {
    int t = blockIdx.x;
    int lane = threadIdx.x;
    float acc[NEXP];
#pragma unroll
    for (int e = 0; e < NEXP; ++e) acc[e] = 0.f;
    for (int c = lane; c < CC; c += 64) {
        float xv = x[t * CC + c];
        const float4* wg = (const float4*)(w_gate + c * NEXP);
        float4 w0 = wg[0], w1 = wg[1];
        acc[0] += xv * w0.x; acc[1] += xv * w0.y;
        acc[2] += xv * w0.z; acc[3] += xv * w0.w;
        acc[4] += xv * w1.x; acc[5] += xv * w1.y;
        acc[6] += xv * w1.z; acc[7] += xv * w1.w;
    }
#pragma unroll
    for (int e = 0; e < NEXP; ++e) {
        for (int off = 32; off > 0; off >>= 1)
            acc[e] += __shfl_down(acc[e], off, 64);
    }
    if (lane == 0) {
        float m = acc[0];
#pragma unroll
        for (int e = 1; e < NEXP; ++e) m = fmaxf(m, acc[e]);
        float p[NEXP]; float s = 0.f;
#pragma unroll
        for (int e = 0; e < NEXP; ++e) { p[e] = expf(acc[e] - m); s += p[e]; }
        float inv_s = 1.f / s;
#pragma unroll
        for (int e = 0; e < NEXP; ++e) p[e] *= inv_s;
        int i0 = 0;
#pragma unroll
        for (int e = 1; e < NEXP; ++e) if (p[e] > p[i0]) i0 = e;
        int i1 = (i0 == 0) ? 1 : 0;
#pragma unroll
        for (int e = 0; e < NEXP; ++e) if (e != i0 && p[e] > p[i1]) i1 = e;
        float p0 = p[i0], p1 = p[i1];
        float inv = 1.f / (p0 + p1);
        top_p[t * 2 + 0] = p0 * inv;
        top_p[t * 2 + 1] = p1 * inv;
        int pos0 = atomicAdd(&counts[i0], 1);
        tok_list[i0 * NTOK + pos0] = t * 2 + 0;
        int pos1 = atomicAdd(&counts[i1], 1);
        tok_list[i1 * NTOK + pos1] = t * 2 + 1;
    }
}

// ---------- weight permutes: de-stride experts, fp32 -> bf16 ----------
// wfc_b[e][c][h] = bf16( w_fc[c*H*NE + h*NE + e] )
__global__ void permute_fc(const float* __restrict__ w_fc,
                           unsigned short* __restrict__ wfc_b) {
    int tid = blockIdx.x * 256 + threadIdx.x;      // 0 .. 8*768*768-1
    int hq = tid % (HH / 4);
    int rem = tid / (HH / 4);
    int c = rem % CC;
    int e = rem / CC;
    int h = hq * 4;
    int in_base = c * (HH * NEXP) + h * NEXP + e;
    ushort4 st;
    st.x = f2bf(w_fc[in_base + 0 * NEXP]);
    st.y = f2bf(w_fc[in_base + 1 * NEXP]);
    st.z = f2bf(w_fc[in_base + 2 * NEXP]);
    st.w = f2bf(w_fc[in_base + 3 * NEXP]);
    *(ushort4*)(wfc_b + (e * CC + c) * HH + h) = st;
}

// Reference: wp = w_proj.reshape(H, C, NE)  ->  wp[h][c][e] = flat[h*C*NE + c*NE + e]
// wp_b[e][h][c] = bf16( wp[h][c][e] )
__global__ void permute_proj(const float* __restrict__ w_proj,
                             unsigned short* __restrict__ wp_b) {
    int tid = blockIdx.x * 256 + threadIdx.x;      // 0 .. 8*3072*192-1
    int cq = tid % (CC / 4);
    int rem = tid / (CC / 4);
    int h = rem % HH;
    int e = rem / HH;
    int c = cq * 4;
    int in_base = h * (CC * NEXP) + c * NEXP + e;
    ushort4 st;
    st.x = f2bf(w_proj[in_base + 0 * NEXP]);
    st.y = f2bf(w_proj[in_base + 1 * NEXP]);
    st.z = f2bf(w_proj[in_base + 2 * NEXP]);
    st.w = f2bf(w_proj[in_base + 3 * NEXP]);
    *(ushort4*)(wp_b + (e * HH + h) * CC + c) = st;
}

// ---------- GEMM1: h[ent][n] = gelu( sum_c x[t][c] * wfc_b[e][c][n] ) ----------
// 64x64 tile, 256 threads, 4x4 micro-tile, K-chunks of 16.
__global__ __launch_bounds__(256)
void gemm1_kernel(const float* __restrict__ x,
                  const unsigned short* __restrict__ wfc_b,
                  const int* __restrict__ counts,
                  const int* __restrict__ tok_list,
                  unsigned short* __restrict__ h_buf) {
    int e = blockIdx.z;
    int M = counts[e];
    int m0 = blockIdx.y * 64;
    if (m0 >= M) return;
    int n0 = blockIdx.x * 64;

    __shared__ float As[16][72];   // k-major, padded: stride 72 floats (16B-aligned rows)
    __shared__ float Bs[16][72];

    int tid = threadIdx.x;
    int tx = tid & 15, ty = tid >> 4;
    int ar = tid >> 2, akc = tid & 3;   // A staging: row, k-quad
    int bk = tid >> 4, bc4 = tid & 15;  // B staging: k-row, col-quad

    int t_row = -1;
    if (m0 + ar < M) t_row = tok_list[e * NTOK + m0 + ar] >> 1;

    float acc[4][4] = {};

    for (int c0 = 0; c0 < CC; c0 += 16) {
        float4 av = make_float4(0.f, 0.f, 0.f, 0.f);
        if (t_row >= 0) av = *(const float4*)(x + t_row * CC + c0 + akc * 4);
        ushort4 bv = *(const ushort4*)(wfc_b + (e * CC + c0 + bk) * HH + n0 + bc4 * 4);
        __syncthreads();
        As[akc * 4 + 0][ar] = av.x;
        As[akc * 4 + 1][ar] = av.y;
        As[akc * 4 + 2][ar] = av.z;
        As[akc * 4 + 3][ar] = av.w;
        float4 bf4 = make_float4(bf2f(bv.x), bf2f(bv.y), bf2f(bv.z), bf2f(bv.w));
        *(float4*)&Bs[bk][bc4 * 4] = bf4;
        __syncthreads();
#pragma unroll
        for (int kk = 0; kk < 16; ++kk) {
            float4 a = *(const float4*)&As[kk][ty * 4];
            float4 b = *(const float4*)&Bs[kk][tx * 4];
            float ar4[4] = {a.x, a.y, a.z, a.w};
            float br4[4] = {b.x, b.y, b.z, b.w};
#pragma unroll
            for (int i = 0; i < 4; ++i)
#pragma unroll
                for (int j = 0; j < 4; ++j)
                    acc[i][j] = fmaf(ar4[i], br4[j], acc[i][j]);
        }
    }

#pragma unroll
    for (int i = 0; i < 4; ++i) {
        int row = m0 + ty * 4 + i;
        if (row < M) {
            int ent = tok_list[e * NTOK + row];
            ushort4 st;
            st.x = f2bf(gelu_tanh(acc[i][0]));
            st.y = f2bf(gelu_tanh(acc[i][1]));
            st.z = f2bf(gelu_tanh(acc[i][2]));
            st.w = f2bf(gelu_tanh(acc[i][3]));
            *(ushort4*)(h_buf + ent * HH + n0 + tx * 4) = st;
        }
    }
}

// ---------- GEMM2: out[t][n] += p * sum_h h[ent][h] * wp_b[e][h][n] ----------
__global__ __launch_bounds__(256)
void gemm2_kernel(const unsigned short* __restrict__ h_buf,
                  const unsigned short* __restrict__ wp_b,
                  const int* __restrict__ counts,
                  const int* __restrict__ tok_list,
                  const float* __restrict__ top_p,
                  float* __restrict__ out) {
    int e = blockIdx.z;
    int M = counts[e];
    int m0 = blockIdx.y * 64;
    if (m0 >= M) return;
    int n0 = blockIdx.x * 64;

    __shared__ float As[16][72];
    __shared__ float Bs[16][72];

    int tid = threadIdx.x;
    int tx = tid & 15, ty = tid >> 4;
    int ar = tid >> 2, akc = tid & 3;
    int bk = tid >> 4, bc4 = tid & 15;

    int ent_row = -1;
    if (m0 + ar < M) ent_row = tok_list[e * NTOK + m0 + ar];

    float acc[4][4] = {};

    for (int c0 = 0; c0 < HH; c0 += 16) {
        float4 af4 = make_float4(0.f, 0.f, 0.f, 0.f);
        if (ent_row >= 0) {
            ushort4 au = *(const ushort4*)(h_buf + ent_row * HH + c0 + akc * 4);
            af4 = make_float4(bf2f(au.x), bf2f(au.y), bf2f(au.z), bf2f(au.w));
        }
        ushort4 bv = *(const ushort4*)(wp_b + (e * HH + c0 + bk) * CC + n0 + bc4 * 4);
        __syncthreads();
        As[akc * 4 + 0][ar] = af4.x;
        As[akc * 4 + 1][ar] = af4.y;
        As[akc * 4 + 2][ar] = af4.z;
        As[akc * 4 + 3][ar] = af4.w;
        float4 bf4 = make_float4(bf2f(bv.x), bf2f(bv.y), bf2f(bv.z), bf2f(bv.w));
        *(float4*)&Bs[bk][bc4 * 4] = bf4;
        __syncthreads();
#pragma unroll
        for (int kk = 0; kk < 16; ++kk) {
            float4 a = *(const float4*)&As[kk][ty * 4];
            float4 b = *(const float4*)&Bs[kk][tx * 4];
            float ar4[4] = {a.x, a.y, a.z, a.w};
            float br4[4] = {b.x, b.y, b.z, b.w};
#pragma unroll
            for (int i = 0; i < 4; ++i)
#pragma unroll
                for (int j = 0; j < 4; ++j)
                    acc[i][j] = fmaf(ar4[i], br4[j], acc[i][j]);
        }
    }

#pragma unroll
    for (int i = 0; i < 4; ++i) {
        int row = m0 + ty * 4 + i;
        if (row < M) {
            int ent = tok_list[e * NTOK + row];
            int t = ent >> 1;
            float p = top_p[ent];
#pragma unroll
            for (int j = 0; j < 4; ++j)
                atomicAdd(&out[t * CC + n0 + tx * 4 + j], acc[i][j] * p);
        }
    }
}

// ---------- launch ----------
extern "C" void kernel_launch(void* const* d_in, const int* in_sizes, int n_in,
                              void* d_out, int out_size, void* d_ws, size_t ws_size,
                              hipStream_t stream) {
    const float* x      = (const float*)d_in[0];
    const float* w_fc   = (const float*)d_in[1];
    const float* w_proj = (const float*)d_in[2];
    const float* w_gate = (const float*)d_in[3];
    float* out = (float*)d_out;

    char* ws = (char*)d_ws;
    float* top_p   = (float*)ws;                        // 4096 floats (16 KB)
    int*   counts  = (int*)(ws + 16384);                // 8 ints
    int*   tok_list= (int*)(ws + 16640);                // 8*2048 ints (64 KB)
    unsigned short* wfc_b = (unsigned short*)(ws + 131072);          // 37.75 MB
    unsigned short* wp_b  = wfc_b + (size_t)NEXP * CC * HH;          // 37.75 MB
    unsigned short* h_buf = wp_b  + (size_t)NEXP * HH * CC;          // 25.2 MB

    hipMemsetAsync(d_out, 0, (size_t)NTOK * CC * sizeof(float), stream);
    hipMemsetAsync(counts, 0, NEXP * sizeof(int), stream);

    router_kernel<<<NTOK, 64, 0, stream>>>(x, w_gate, top_p, counts, tok_list);
    permute_fc  <<<(NEXP * CC * (HH / 4)) / 256, 256, 0, stream>>>(w_fc, wfc_b);
    permute_proj<<<(NEXP * HH * (CC / 4)) / 256, 256, 0, stream>>>(w_proj, wp_b);

    gemm1_kernel<<<dim3(HH / 64, NTOK / 64, NEXP), 256, 0, stream>>>(
        x, wfc_b, counts, tok_list, h_buf);
    gemm2_kernel<<<dim3(CC / 64, NTOK / 64, NEXP), 256, 0, stream>>>(
        h_buf, wp_b, counts, tok_list, top_p, out);
}

// Round 2
// 393.625 us; speedup vs baseline: 2.9009x; 2.9009x over previous
//
#include <hip/hip_runtime.h>
#include <hip/hip_bf16.h>
#include <math.h>

#define BB 2
#define TT 1024
#define CC 768
#define HH 3072
#define NEXP 8
#define NTOK (BB*TT)        // 2048 tokens
#define CAP 1024            // per-expert slab capacity (mean count ~512, std ~21)

typedef __attribute__((ext_vector_type(8))) short short8;
typedef __attribute__((ext_vector_type(4))) float float4v;

typedef const __attribute__((address_space(1))) void* gptr_t;
typedef __attribute__((address_space(3))) void* sptr_t;

// ---------- helpers ----------
__device__ __forceinline__ unsigned short f2bf(float f) {
    unsigned int u = __float_as_uint(f);
    unsigned int r = (u + 0x7fffu + ((u >> 16) & 1u)) >> 16;
    return (unsigned short)r;
}
__device__ __forceinline__ float gelu_tanh(float v) {
    // 0.5*v*(1+tanh(k0*(v+k1*v^3))) == v * sigmoid(2*k0*(v+k1*v^3))
    const float k2 = 2.0f * 0.7978845608028654f;
    const float k1 = 0.044715f;
    float z = k2 * (v + k1 * v * v * v);
    return v / (1.0f + __expf(-z));
}

// ---------- router: logits, softmax, top-2, renorm, bucket ----------
__global__ void router_kernel(const float* __restrict__ x,
                              const float* __restrict__ w_gate,
                              float* __restrict__ top_p,
                              int* __restrict__ counts,
                              int* __restrict__ tok_list) {
    int t = blockIdx.x;
    int lane = threadIdx.x;
    float acc[NEXP];
#pragma unroll
    for (int e = 0; e < NEXP; ++e) acc[e] = 0.f;
    for (int c = lane; c < CC; c += 64) {
        float xv = x[t * CC + c];
        const float4* wg = (const float4*)(w_gate + c * NEXP);
        float4 w0 = wg[0], w1 = wg[1];
        acc[0] += xv * w0.x; acc[1] += xv * w0.y;
        acc[2] += xv * w0.z; acc[3] += xv * w0.w;
        acc[4] += xv * w1.x; acc[5] += xv * w1.y;
        acc[6] += xv * w1.z; acc[7] += xv * w1.w;
    }
#pragma unroll
    for (int e = 0; e < NEXP; ++e) {
        for (int off = 32; off > 0; off >>= 1)
            acc[e] += __shfl_down(acc[e], off, 64);
    }
    if (lane == 0) {
        float m = acc[0];
#pragma unroll
        for (int e = 1; e < NEXP; ++e) m = fmaxf(m, acc[e]);
        float p[NEXP]; float s = 0.f;
#pragma unroll
        for (int e = 0; e < NEXP; ++e) { p[e] = expf(acc[e] - m); s += p[e]; }
        float inv_s = 1.f / s;
#pragma unroll
        for (int e = 0; e < NEXP; ++e) p[e] *= inv_s;
        int i0 = 0;
#pragma unroll
        for (int e = 1; e < NEXP; ++e) if (p[e] > p[i0]) i0 = e;
        int i1 = (i0 == 0) ? 1 : 0;
#pragma unroll
        for (int e = 0; e < NEXP; ++e) if (e != i0 && p[e] > p[i1]) i1 = e;
        float p0 = p[i0], p1 = p[i1];
        float inv = 1.f / (p0 + p1);
        top_p[t * 2 + 0] = p0 * inv;
        top_p[t * 2 + 1] = p1 * inv;
        int pos0 = atomicAdd(&counts[i0], 1);
        if (pos0 < CAP) tok_list[i0 * NTOK + pos0] = t * 2 + 0;
        int pos1 = atomicAdd(&counts[i1], 1);
        if (pos1 < CAP) tok_list[i1 * NTOK + pos1] = t * 2 + 1;
    }
}

// ---------- weight permute: In[a][b*8+e] fp32 -> Out[e][b][a] bf16 ----------
// 32x32 (a x b) tile, all 8 experts per tile (they share cache lines).
__global__ __launch_bounds__(256)
void permute_w(const float* __restrict__ In, unsigned short* __restrict__ Out,
               int Adim, int Bdim) {
    __shared__ unsigned short L[32 * 256];   // [a 0..31][k=b_local*8+e 0..255]
    int a0 = blockIdx.x * 32, b0 = blockIdx.y * 32;
    int t = threadIdx.x;
#pragma unroll
    for (int j = 0; j < 8; ++j) {
        int idx = j * 256 + t;          // 0..2047 float4 chunks
        int ar = idx >> 6;              // 64 float4 per a-row
        int wi = idx & 63;
        const float4 v = *(const float4*)(In + (size_t)(a0 + ar) * Bdim * 8 + b0 * 8 + wi * 4);
        ushort4 s;
        s.x = f2bf(v.x); s.y = f2bf(v.y); s.z = f2bf(v.z); s.w = f2bf(v.w);
        *(ushort4*)&L[ar * 256 + wi * 4] = s;
    }
    __syncthreads();
    // thread t -> (b_local = t>>3, e = t&7), k index == t; gather 32 a-values
    unsigned short tmp[32];
#pragma unroll
    for (int a = 0; a < 32; ++a) tmp[a] = L[a * 256 + t];
    int b = b0 + (t >> 3), e = t & 7;
    unsigned short* dst = Out + ((size_t)e * Bdim + b) * Adim + a0;
#pragma unroll
    for (int j = 0; j < 8; ++j) {
        ushort4 s; s.x = tmp[j*4+0]; s.y = tmp[j*4+1]; s.z = tmp[j*4+2]; s.w = tmp[j*4+3];
        *(ushort4*)(dst + j * 4) = s;
    }
}

// ---------- gather x into per-expert bf16 slabs (zero the pad rows) ----------
__global__ void gather_x(const float* __restrict__ x,
                         const int* __restrict__ counts,
                         const int* __restrict__ tok_list,
                         unsigned short* __restrict__ xg) {
    int pos = blockIdx.x;              // 0 .. NEXP*CAP-1
    int e = pos >> 10, i = pos & (CAP - 1);
    int M = counts[e]; if (M > CAP) M = CAP;
    int Mr = (M + 127) & ~127; if (Mr > CAP) Mr = CAP;
    if (i >= Mr) return;
    int c = threadIdx.x * 4;           // 192 threads x 4
    unsigned short* dst = xg + (size_t)pos * CC + c;
    ushort4 s;
    if (i < M) {
        int tk = tok_list[e * NTOK + i] >> 1;
        float4 v = *(const float4*)(x + (size_t)tk * CC + c);
        s.x = f2bf(v.x); s.y = f2bf(v.y); s.z = f2bf(v.z); s.w = f2bf(v.w);
    } else {
        s.x = s.y = s.z = s.w = 0;
    }
    *(ushort4*)dst = s;
}

// ---------- MFMA GEMM1: h_slab = gelu(xg @ wfc_b^T), per expert ----------
// A: xg [e][CAP][CC] bf16 (M x K). B: wfc_b [e][HH][CC] bf16 (N x K).
// 128x128 tile, BK=32, 4 waves each computing 64x64 via 4x4 mfma_16x16x32.
__global__ __launch_bounds__(256)
void gemm1_mfma(const unsigned short* __restrict__ xg,
                const unsigned short* __restrict__ wfc_b,
                const int* __restrict__ counts,
                unsigned short* __restrict__ h_slab) {
    int e = blockIdx.z;
    int M = counts[e]; if (M > CAP) M = CAP;
    int m0 = blockIdx.y * 128;
    if (m0 >= M) return;
    int n0 = blockIdx.x * 128;

    __shared__ unsigned short As[128 * 32];
    __shared__ unsigned short Bs[128 * 32];

    int tid = threadIdx.x;
    int wave = tid >> 6, lane = tid & 63;
    int wm = wave >> 1, wn = wave & 1;
    int quad = lane >> 4, l16 = lane & 15;

    const unsigned short* aBase = xg + ((size_t)e * CAP + m0) * CC;
    const unsigned short* bBase = wfc_b + ((size_t)e * HH + n0) * CC;

    int srow_lo = lane >> 2;            // 0..15 within 16-row group
    int schunk = (lane & 3) * 8;        // 16B chunk (8 ushorts)

    float4v acc[4][4];
#pragma unroll
    for (int i = 0; i < 4; ++i)
#pragma unroll
        for (int j = 0; j < 4; ++j)
#pragma unroll
            for (int r = 0; r < 4; ++r) acc[i][j][r] = 0.f;

    for (int k0 = 0; k0 < CC; k0 += 32) {
        __syncthreads();
#pragma unroll
        for (int q = 0; q < 2; ++q) {
            int r = wave * 32 + q * 16 + srow_lo;
            __builtin_amdgcn_global_load_lds(
                (gptr_t)(aBase + (size_t)r * CC + k0 + schunk),
                (sptr_t)(As + (wave * 32 + q * 16) * 32), 16, 0, 0);
            __builtin_amdgcn_global_load_lds(
                (gptr_t)(bBase + (size_t)r * CC + k0 + schunk),
                (sptr_t)(Bs + (wave * 32 + q * 16) * 32), 16, 0, 0);
        }
        __syncthreads();
        short8 af[4], bf[4];
#pragma unroll
        for (int mt = 0; mt < 4; ++mt)
            af[mt] = *(const short8*)&As[(wm * 64 + mt * 16 + l16) * 32 + quad * 8];
#pragma unroll
        for (int nt = 0; nt < 4; ++nt)
            bf[nt] = *(const short8*)&Bs[(wn * 64 + nt * 16 + l16) * 32 + quad * 8];
#pragma unroll
        for (int mt = 0; mt < 4; ++mt)
#pragma unroll
            for (int nt = 0; nt < 4; ++nt)
                acc[mt][nt] = __builtin_amdgcn_mfma_f32_16x16x32_bf16(
                    af[mt], bf[nt], acc[mt][nt], 0, 0, 0);
    }

    // epilogue: gelu -> bf16; pad rows get gelu(0)=0 (zero A rows)
#pragma unroll
    for (int mt = 0; mt < 4; ++mt) {
#pragma unroll
        for (int r = 0; r < 4; ++r) {
            int m = m0 + wm * 64 + mt * 16 + quad * 4 + r;
            unsigned short* orow = h_slab + ((size_t)e * CAP + m) * HH + n0 + wn * 64 + l16;
#pragma unroll
            for (int nt = 0; nt < 4; ++nt)
                orow[nt * 16] = f2bf(gelu_tanh(acc[mt][nt][r]));
        }
    }
}

// ---------- MFMA GEMM2: o_ent[ent] += h_slab @ wp_b^T (split-K=4) ----------
// A: h_slab [e][CAP][HH]. B: wp_b [e][CC][HH] (N x K). Scatter rows by ent.
__global__ __launch_bounds__(256)
void gemm2_mfma(const unsigned short* __restrict__ h_slab,
                const unsigned short* __restrict__ wp_b,
                const int* __restrict__ counts,
                const int* __restrict__ tok_list,
                float* __restrict__ o_ent) {
    int e = blockIdx.z;
    int M = counts[e]; if (M > CAP) M = CAP;
    int m0 = blockIdx.y * 128;
    if (m0 >= M) return;
    int n0 = (blockIdx.x >> 2) * 128;
    int ks = blockIdx.x & 3;           // K slice [ks*768, ks*768+768)

    __shared__ unsigned short As[128 * 32];
    __shared__ unsigned short Bs[128 * 32];

    int tid = threadIdx.x;
    int wave = tid >> 6, lane = tid & 63;
    int wm = wave >> 1, wn = wave & 1;
    int quad = lane >> 4, l16 = lane & 15;

    const unsigned short* aBase = h_slab + ((size_t)e * CAP + m0) * HH;
    const unsigned short* bBase = wp_b + ((size_t)e * CC + n0) * HH;

    int srow_lo = lane >> 2;
    int schunk = (lane & 3) * 8;

    float4v acc[4][4];
#pragma unroll
    for (int i = 0; i < 4; ++i)
#pragma unroll
        for (int j = 0; j < 4; ++j)
#pragma unroll
            for (int r = 0; r < 4; ++r) acc[i][j][r] = 0.f;

    int kend = ks * 768 + 768;
    for (int k0 = ks * 768; k0 < kend; k0 += 32) {
        __syncthreads();
#pragma unroll
        for (int q = 0; q < 2; ++q) {
            int r = wave * 32 + q * 16 + srow_lo;
            __builtin_amdgcn_global_load_lds(
                (gptr_t)(aBase + (size_t)r * HH + k0 + schunk),
                (sptr_t)(As + (wave * 32 + q * 16) * 32), 16, 0, 0);
            __builtin_amdgcn_global_load_lds(
                (gptr_t)(bBase + (size_t)r * HH + k0 + schunk),
                (sptr_t)(Bs + (wave * 32 + q * 16) * 32), 16, 0, 0);
        }
        __syncthreads();
        short8 af[4], bf[4];
#pragma unroll
        for (int mt = 0; mt < 4; ++mt)
            af[mt] = *(const short8*)&As[(wm * 64 + mt * 16 + l16) * 32 + quad * 8];
#pragma unroll
        for (int nt = 0; nt < 4; ++nt)
            bf[nt] = *(const short8*)&Bs[(wn * 64 + nt * 16 + l16) * 32 + quad * 8];
#pragma unroll
        for (int mt = 0; mt < 4; ++mt)
#pragma unroll
            for (int nt = 0; nt < 4; ++nt)
                acc[mt][nt] = __builtin_amdgcn_mfma_f32_16x16x32_bf16(
                    af[mt], bf[nt], acc[mt][nt], 0, 0, 0);
    }

#pragma unroll
    for (int mt = 0; mt < 4; ++mt) {
#pragma unroll
        for (int r = 0; r < 4; ++r) {
            int m = m0 + wm * 64 + mt * 16 + quad * 4 + r;
            if (m < M) {
                int ent = tok_list[e * NTOK + m];
                float* orow = o_ent + (size_t)ent * CC + n0 + wn * 64 + l16;
#pragma unroll
                for (int nt = 0; nt < 4; ++nt)
                    atomicAdd(&orow[nt * 16], acc[mt][nt][r]);
            }
        }
    }
}

// ---------- combine: out[t] = p0*o_ent[2t] + p1*o_ent[2t+1] ----------
__global__ void combine_kernel(const float* __restrict__ o_ent,
                               const float* __restrict__ top_p,
                               float* __restrict__ out) {
    int idx = blockIdx.x * 256 + threadIdx.x;   // per float4
    int t = idx / (CC / 4);
    int c = (idx % (CC / 4)) * 4;
    float p0 = top_p[2 * t], p1 = top_p[2 * t + 1];
    const float4 a = *(const float4*)(o_ent + (size_t)(2 * t) * CC + c);
    const float4 b = *(const float4*)(o_ent + (size_t)(2 * t + 1) * CC + c);
    float4 r;
    r.x = p0 * a.x + p1 * b.x;
    r.y = p0 * a.y + p1 * b.y;
    r.z = p0 * a.z + p1 * b.z;
    r.w = p0 * a.w + p1 * b.w;
    *(float4*)(out + (size_t)t * CC + c) = r;
}

// ---------- launch ----------
extern "C" void kernel_launch(void* const* d_in, const int* in_sizes, int n_in,
                              void* d_out, int out_size, void* d_ws, size_t ws_size,
                              hipStream_t stream) {
    const float* x      = (const float*)d_in[0];
    const float* w_fc   = (const float*)d_in[1];
    const float* w_proj = (const float*)d_in[2];
    const float* w_gate = (const float*)d_in[3];
    float* out = (float*)d_out;

    char* ws = (char*)d_ws;
    size_t off = 0;
    float* top_p    = (float*)(ws + off); off += NTOK * 2 * sizeof(float);        // 16 KB
    int*   counts   = (int*)(ws + off);   off += 256;                             // 8 ints (padded)
    int*   tok_list = (int*)(ws + off);   off += (size_t)NEXP * NTOK * 4;         // 64 KB
    off = (off + 255) & ~(size_t)255;
    unsigned short* wfc_b  = (unsigned short*)(ws + off); off += (size_t)NEXP*HH*CC*2;  // 37.75 MB
    unsigned short* wp_b   = (unsigned short*)(ws + off); off += (size_t)NEXP*CC*HH*2;  // 37.75 MB
    unsigned short* xg     = (unsigned short*)(ws + off); off += (size_t)NEXP*CAP*CC*2; // 12.6 MB
    unsigned short* h_slab = (unsigned short*)(ws + off); off += (size_t)NEXP*CAP*HH*2; // 50.3 MB
    float*          o_ent  = (float*)(ws + off);          off += (size_t)NTOK*2*CC*4;   // 12.6 MB

    hipMemsetAsync(counts, 0, 256, stream);
    hipMemsetAsync(o_ent, 0, (size_t)NTOK * 2 * CC * 4, stream);

    router_kernel<<<NTOK, 64, 0, stream>>>(x, w_gate, top_p, counts, tok_list);
    // w_fc: In[c][h*8+e], Adim=CC, Bdim=HH -> wfc_b[e][h][c]
    permute_w<<<dim3(CC / 32, HH / 32), 256, 0, stream>>>(w_fc, wfc_b, CC, HH);
    // w_proj: In[h][c*8+e], Adim=HH, Bdim=CC -> wp_b[e][c][h]
    permute_w<<<dim3(HH / 32, CC / 32), 256, 0, stream>>>(w_proj, wp_b, HH, CC);
    gather_x<<<NEXP * CAP, 192, 0, stream>>>(x, counts, tok_list, xg);

    gemm1_mfma<<<dim3(HH / 128, CAP / 128, NEXP), 256, 0, stream>>>(
        xg, wfc_b, counts, h_slab);
    gemm2_mfma<<<dim3((CC / 128) * 4, CAP / 128, NEXP), 256, 0, stream>>>(
        h_slab, wp_b, counts, tok_list, o_ent);
    combine_kernel<<<(NTOK * CC / 4) / 256, 256, 0, stream>>>(o_ent, top_p, out);
}